// Round 2
// baseline (33.895 us; speedup 1.0000x reference)
//
#include <hip/hip_runtime.h>
#include <math.h>

// GaussianMixtureLoss: loss = CONST - mean_{b,n}( ln sum_m exp(p·g - |g|²/2) - |p|²/2 )
// B=4, N=4096, M=4096, D=3, SIGMA=1.
#define BATCH 4
#define NPTS 4096
#define NMIX 4096
#define NCHUNK 64
#define MCHUNK 64           // NMIX / NCHUNK
#define THREADS 256
#define PPT 4               // points per thread (2x float2 packs)

#define L2E 1.4426950408889634f
#define LN2 0.6931471805599453f
#define CONST_TERM 0.9189385332046727f  // 0.5*log(2*pi)

typedef float v2f __attribute__((ext_vector_type(2)));

__device__ __forceinline__ float fast_exp2(float x) {
#if __has_builtin(__builtin_amdgcn_exp2f)
  return __builtin_amdgcn_exp2f(x);   // raw v_exp_f32
#else
  return exp2f(x);
#endif
}
__device__ __forceinline__ float fast_log2(float x) {
#if __has_builtin(__builtin_amdgcn_logf)
  return __builtin_amdgcn_logf(x);    // raw v_log_f32
#else
  return log2f(x);
#endif
}

// K1: partial[z*16384 + b*4096 + n] = sum_{m in chunk z} exp2( p·g' - w' )
// where g' = L2E*g, w' = 0.5*L2E*|g|². Block: 1024 points x 64 mixture comps.
__global__ __launch_bounds__(THREADS) void gm_partial(
    const float* __restrict__ pred, const float* __restrict__ gt,
    float* __restrict__ partial) {
  __shared__ float4 gsh[MCHUNK];  // (L2E*gx, L2E*gy, L2E*gz, 0.5*L2E*|g|²) : 1 KB

  const int b = blockIdx.y;
  const int n0 = blockIdx.x * (THREADS * PPT);
  const int m0 = blockIdx.z * MCHUNK;
  const int t = threadIdx.x;

  if (t < MCHUNK) {
    const float* g = gt + ((size_t)(b * NMIX + m0 + t)) * 3;
    float gx = g[0], gy = g[1], gz = g[2];
    gsh[t] = make_float4(L2E * gx, L2E * gy, L2E * gz,
                         0.5f * L2E * (gx * gx + gy * gy + gz * gz));
  }

  // load 4 points: n0+t, n0+256+t, n0+512+t, n0+768+t, pack as 2x float2
  const float* p0 = pred + ((size_t)(b * NPTS + n0 + t)) * 3;
  const float* p1 = p0 + 256 * 3;
  const float* p2 = p0 + 512 * 3;
  const float* p3 = p0 + 768 * 3;
  v2f pxA = {p0[0], p1[0]}, pyA = {p0[1], p1[1]}, pzA = {p0[2], p1[2]};
  v2f pxB = {p2[0], p3[0]}, pyB = {p2[1], p3[1]}, pzB = {p2[2], p3[2]};

  __syncthreads();

  v2f accA = {0.f, 0.f}, accB = {0.f, 0.f};
#pragma unroll 8
  for (int j = 0; j < MCHUNK; ++j) {
    float4 gv = gsh[j];                       // uniform broadcast read
    v2f bx = {gv.x, gv.x};
    v2f by = {gv.y, gv.y};
    v2f bz = {gv.z, gv.z};
    v2f nw = {-gv.w, -gv.w};
    v2f tA = __builtin_elementwise_fma(pxA, bx,
             __builtin_elementwise_fma(pyA, by,
             __builtin_elementwise_fma(pzA, bz, nw)));
    v2f tB = __builtin_elementwise_fma(pxB, bx,
             __builtin_elementwise_fma(pyB, by,
             __builtin_elementwise_fma(pzB, bz, nw)));
    v2f eA = {fast_exp2(tA.x), fast_exp2(tA.y)};
    v2f eB = {fast_exp2(tB.x), fast_exp2(tB.y)};
    accA += eA;
    accB += eB;
  }

  float* dst = partial + (size_t)blockIdx.z * (BATCH * NPTS) + b * NPTS + n0 + t;
  dst[0]   = accA.x;
  dst[256] = accA.y;
  dst[512] = accB.x;
  dst[768] = accB.y;
}

// K2: per-point combine (plain add across 64 chunks, coalesced strided reads),
// log, subtract |p|²/2, per-block reduce -> blockpart[64].
__global__ __launch_bounds__(256) void gm_combine(
    const float* __restrict__ pred, const float* __restrict__ partial,
    float* __restrict__ blockpart) {
  const int gp = blockIdx.x * 256 + threadIdx.x;

  float s0 = 0.f, s1 = 0.f, s2 = 0.f, s3 = 0.f;
#pragma unroll
  for (int z = 0; z < NCHUNK; z += 4) {
    s0 += partial[(size_t)(z + 0) * (BATCH * NPTS) + gp];
    s1 += partial[(size_t)(z + 1) * (BATCH * NPTS) + gp];
    s2 += partial[(size_t)(z + 2) * (BATCH * NPTS) + gp];
    s3 += partial[(size_t)(z + 3) * (BATCH * NPTS) + gp];
  }
  float sum = (s0 + s1) + (s2 + s3);

  const float* p = pred + (size_t)gp * 3;
  float halfp2 = 0.5f * (p[0] * p[0] + p[1] * p[1] + p[2] * p[2]);
  float ll = LN2 * fast_log2(sum) - halfp2;

  for (int off = 32; off > 0; off >>= 1) ll += __shfl_down(ll, off, 64);
  __shared__ float wsum[4];
  const int wave = threadIdx.x >> 6, lane = threadIdx.x & 63;
  if (lane == 0) wsum[wave] = ll;
  __syncthreads();
  if (threadIdx.x == 0)
    blockpart[blockIdx.x] = (wsum[0] + wsum[1]) + (wsum[2] + wsum[3]);
}

// K3: final reduce of 64 block partials -> loss scalar.
__global__ __launch_bounds__(64) void gm_final(
    const float* __restrict__ blockpart, float* __restrict__ out) {
  float v = blockpart[threadIdx.x];
  for (int off = 32; off > 0; off >>= 1) v += __shfl_down(v, off, 64);
  if (threadIdx.x == 0)
    out[0] = CONST_TERM - v * (1.0f / (float)(BATCH * NPTS));
}

extern "C" void kernel_launch(void* const* d_in, const int* in_sizes, int n_in,
                              void* d_out, int out_size, void* d_ws, size_t ws_size,
                              hipStream_t stream) {
  const float* pred = (const float*)d_in[0];
  const float* gt   = (const float*)d_in[1];
  float* out = (float*)d_out;

  float* partial   = (float*)d_ws;                              // 64*16384 floats = 4 MB
  float* blockpart = partial + (size_t)NCHUNK * BATCH * NPTS;   // +64 floats

  dim3 g1(NPTS / (THREADS * PPT), BATCH, NCHUNK);  // (4, 4, 64) = 1024 blocks
  gm_partial<<<g1, THREADS, 0, stream>>>(pred, gt, partial);

  gm_combine<<<(BATCH * NPTS) / 256, 256, 0, stream>>>(pred, partial, blockpart);

  gm_final<<<1, 64, 0, stream>>>(blockpart, out);
}